// Round 3
// baseline (2111.822 us; speedup 1.0000x reference)
//
#include <hip/hip_runtime.h>
#include <cfloat>
#include <climits>

// B=4, N_DAY=2048, N_CELLS=8192, D_MICRO=11, D=256, TOPK=32
static constexpr float SCALE = 0.0625f;  // 256^-0.5

// ---------------- kernel A: x_micro = micro @ mp_w + mp_b  → outX region ----
__global__ __launch_bounds__(256) void k_micro_mlp(
    const float* __restrict__ micro, const float* __restrict__ mpw,
    const float* __restrict__ mpb, float* __restrict__ xm) {
  const int r0 = blockIdx.x * 8;
  const int tid = threadIdx.x;
  __shared__ float ml[8][12];
  if (tid < 88) ml[tid / 11][tid % 11] = micro[(size_t)(r0 + tid / 11) * 11 + tid % 11];
  __syncthreads();
  const int d = tid;
  const float bias = mpb[d];
  float acc[8];
#pragma unroll
  for (int r = 0; r < 8; ++r) acc[r] = bias;
#pragma unroll
  for (int i = 0; i < 11; ++i) {
    const float w = mpw[i * 256 + d];
#pragma unroll
    for (int r = 0; r < 8; ++r) acc[r] = fmaf(ml[r][i], w, acc[r]);
  }
#pragma unroll
  for (int r = 0; r < 8; ++r) xm[(size_t)(r0 + r) * 256 + d] = acc[r];
}

// ---------------- kernel B: C[M x 256] = A[M x 256] @ W[256 x 256] ----------
__global__ __launch_bounds__(256) void k_gemm256(
    const float* __restrict__ A, const float* __restrict__ W,
    float* __restrict__ C, int ntn) {
  const int bx = blockIdx.x;
  const int m0 = (bx / ntn) * 64, n0 = (bx % ntn) * 64;
  const int tid = threadIdx.x;
  __shared__ __align__(16) float Al[16][72];  // k-major [k][m]
  __shared__ __align__(16) float Wl[16][72];  // k-major [k][n]
  float acc[4][4] = {};
  const int mg = tid >> 4, ng = tid & 15;
  for (int k0 = 0; k0 < 256; k0 += 16) {
    __syncthreads();
    {
      const int m = tid >> 2, ko = (tid & 3) << 2;
      const float4 a = *(const float4*)&A[(size_t)(m0 + m) * 256 + k0 + ko];
      Al[ko + 0][m] = a.x; Al[ko + 1][m] = a.y; Al[ko + 2][m] = a.z; Al[ko + 3][m] = a.w;
      const int kr = tid >> 4, no = (tid & 15) << 2;
      *(float4*)&Wl[kr][no] = *(const float4*)&W[(size_t)(k0 + kr) * 256 + n0 + no];
    }
    __syncthreads();
#pragma unroll
    for (int kk = 0; kk < 16; ++kk) {
      const float4 av = *(const float4*)&Al[kk][mg << 2];
      const float4 wv = *(const float4*)&Wl[kk][ng << 2];
      const float a_[4] = {av.x, av.y, av.z, av.w};
      const float w_[4] = {wv.x, wv.y, wv.z, wv.w};
#pragma unroll
      for (int i = 0; i < 4; ++i)
#pragma unroll
        for (int j = 0; j < 4; ++j) acc[i][j] = fmaf(a_[i], w_[j], acc[i][j]);
    }
  }
#pragma unroll
  for (int i = 0; i < 4; ++i) {
    float4 o = {acc[i][0], acc[i][1], acc[i][2], acc[i][3]};
    *(float4*)&C[(size_t)(m0 + (mg << 2) + i) * 256 + n0 + (ng << 2)] = o;
  }
}

// ---------------- kernel C: scores + online top-32 --------------------------
// Grid: nb * 64 query-blocks * S cell-parts. Each WG: 32 queries x (8192/S)
// cells, fp32 score GEMM (32x128 tile), register top-32 per query distributed
// over lanes 0..31 of the owning wave. K buffer row stride = 256.
__global__ __launch_bounds__(256) void k_scores_topk(
    const float* __restrict__ Q, const float* __restrict__ K,
    float* __restrict__ tkv, int* __restrict__ tki, int lgS) {
  const int wg = blockIdx.x;
  const int S = 1 << lgS;
  const int part = wg & (S - 1);
  const int qb = (wg >> lgS) & 63;
  const int bl = wg >> (lgS + 6);
  const int qloc = bl * 2048 + qb * 32;
  const float* Qb = Q + (size_t)qloc * 256;
  const float* Kb = K + (size_t)bl * 8192 * 256;
  const int cells = 8192 >> lgS;
  const int ntiles = cells >> 7;
  const int ncand = 32 << lgS;

  __shared__ __align__(16) float Qs[32][36];   // k-major [k][q]
  __shared__ __align__(16) float Kl[32][132];  // k-major [k][c]
  __shared__ __align__(16) float Sl[32][132];  // [q][c]

  const int tid = threadIdx.x;
  const int lane = tid & 63;
  const int qg = tid >> 5, cg = tid & 31;
  const int wq8 = (tid >> 6) * 8;

  float slotv[8], cmin[8];
  int sloti[8], cargm[8];
#pragma unroll
  for (int qq = 0; qq < 8; ++qq) {
    // DISTINCT sentinel indices -> strict total order -> butterfly argmin is
    // wave-uniform (the round-1/2 crash: identical sentinels made cargm
    // diverge per lane, corrupting the slot list).
    slotv[qq] = (lane < 32) ? -FLT_MAX : FLT_MAX;  // lanes>=32 never win argmin
    sloti[qq] = 0x7fff0000 + lane;
    cmin[qq] = -FLT_MAX;
    cargm[qq] = 0;
  }

  for (int ct = 0; ct < ntiles; ++ct) {
    const int c0 = part * cells + ct * 128;
    float acc[4][4] = {};
    for (int kc = 0; kc < 8; ++kc) {
      const int k0 = kc * 32;
      __syncthreads();
      {
        const int q = tid >> 3, k4 = (tid & 7) << 2;
        const float4 qv = *(const float4*)&Qb[(size_t)q * 256 + k0 + k4];
        Qs[k4 + 0][q] = qv.x; Qs[k4 + 1][q] = qv.y; Qs[k4 + 2][q] = qv.z; Qs[k4 + 3][q] = qv.w;
#pragma unroll
        for (int j = 0; j < 4; ++j) {
          const int f = tid + 256 * j;
          const int c = f >> 3, kk4 = (f & 7) << 2;
          const float4 kv4 = *(const float4*)&Kb[(size_t)(c0 + c) * 256 + k0 + kk4];
          Kl[kk4 + 0][c] = kv4.x; Kl[kk4 + 1][c] = kv4.y; Kl[kk4 + 2][c] = kv4.z; Kl[kk4 + 3][c] = kv4.w;
        }
      }
      __syncthreads();
#pragma unroll 8
      for (int kk = 0; kk < 32; ++kk) {
        const float4 av = *(const float4*)&Qs[kk][qg << 2];
        const float4 bv = *(const float4*)&Kl[kk][cg << 2];
        const float a_[4] = {av.x, av.y, av.z, av.w};
        const float b_[4] = {bv.x, bv.y, bv.z, bv.w};
#pragma unroll
        for (int i = 0; i < 4; ++i)
#pragma unroll
          for (int j = 0; j < 4; ++j) acc[i][j] = fmaf(a_[i], b_[j], acc[i][j]);
      }
    }
#pragma unroll
    for (int i = 0; i < 4; ++i) {
      float4 o = {acc[i][0] * SCALE, acc[i][1] * SCALE, acc[i][2] * SCALE, acc[i][3] * SCALE};
      *(float4*)&Sl[(qg << 2) + i][cg << 2] = o;
    }
    __syncthreads();
    // Each wave owns 8 queries; candidates in ascending cell order.
    // jax.lax.top_k ties: value desc, index asc; eviction prefers higher index.
#pragma unroll
    for (int qq = 0; qq < 8; ++qq) {
      const int q = wq8 + qq;
      float cm = cmin[qq];
#pragma unroll
      for (int pass = 0; pass < 2; ++pass) {
        const float v = Sl[q][pass * 64 + lane];
        const int ci = c0 + pass * 64 + lane;
        unsigned long long mask = __ballot(v > cm);
        while (mask) {
          const int src = __ffsll(mask) - 1;
          mask &= mask - 1;
          const float cv = __shfl(v, src);
          const int cidx = __shfl(ci, src);
          if (cv > cm) {
            if (lane == cargm[qq]) { slotv[qq] = cv; sloti[qq] = cidx; }
            float sv = slotv[qq]; int si = sloti[qq]; int ss = lane;
#pragma unroll
            for (int off = 32; off >= 1; off >>= 1) {
              const float ov = __shfl_xor(sv, off);
              const int oi = __shfl_xor(si, off);
              const int os = __shfl_xor(ss, off);
              if (ov < sv || (ov == sv && oi > si)) { sv = ov; si = oi; ss = os; }
            }
            cm = sv;            // strict total order -> uniform across lanes
            cargm[qq] = ss;
          }
        }
      }
      cmin[qq] = cm;
    }
  }
#pragma unroll
  for (int qq = 0; qq < 8; ++qq) {
    if (lane < 32) {
      const size_t q = (size_t)(qloc + wq8 + qq);
      tkv[q * ncand + part * 32 + lane] = slotv[qq];
      tki[q * ncand + part * 32 + lane] = sloti[qq];
    }
  }
}

// ---------------- kernel D: merge parts, softmax, context, output proj ------
// context = sum_k w_k * (macro[i_k] @ wv) = (sum_k w_k * macro[i_k]) @ wv
// so V is never materialized.
__global__ __launch_bounds__(256) void k_finalize(
    const float* __restrict__ macro, const float* __restrict__ wv,
    const float* __restrict__ tkv, const int* __restrict__ tki,
    const float* __restrict__ opw, const float* __restrict__ opb,
    float* __restrict__ outX, float* __restrict__ outW, float* __restrict__ outI,
    int b0, int lgS) {
  const int ql = blockIdx.x;
  const int bl = ql >> 11;
  const size_t gq = (size_t)b0 * 2048 + ql;
  const int ncand = 32 << lgS;  // 64 or 128
  const int tid = threadIdx.x;
  __shared__ float wts[32];
  __shared__ int sidx[32];
  __shared__ float mbar[256];
  __shared__ float ctx[256];
  if (tid < 32) { wts[tid] = 0.f; sidx[tid] = 0; }  // defensive: no fault path
  __syncthreads();
  if (tid < 64) {
    const int lane = tid;
    float v0 = tkv[(size_t)ql * ncand + lane];
    int   i0 = tki[(size_t)ql * ncand + lane];
    float v1 = -FLT_MAX;
    int   i1 = 0x7ffe0000 + lane;  // distinct, never rank<32
    if (ncand == 128) {
      v1 = tkv[(size_t)ql * 128 + 64 + lane];
      i1 = tki[(size_t)ql * 128 + 64 + lane];
    }
    int r0 = 0, r1 = 0;
#pragma unroll
    for (int j = 0; j < 64; ++j) {
      const float a0 = __shfl(v0, j); const int c0 = __shfl(i0, j);
      const float a1 = __shfl(v1, j); const int c1 = __shfl(i1, j);
      r0 += (a0 > v0 || (a0 == v0 && c0 < i0)) ? 1 : 0;
      r0 += (a1 > v0 || (a1 == v0 && c1 < i0)) ? 1 : 0;
      r1 += (a0 > v1 || (a0 == v1 && c0 < i1)) ? 1 : 0;
      r1 += (a1 > v1 || (a1 == v1 && c1 < i1)) ? 1 : 0;
    }
    float mv = fmaxf(v0, v1);
#pragma unroll
    for (int off = 32; off >= 1; off >>= 1) mv = fmaxf(mv, __shfl_xor(mv, off));
    const float e0 = (r0 < 32) ? expf(v0 - mv) : 0.f;
    const float e1 = (r1 < 32) ? expf(v1 - mv) : 0.f;
    float s = e0 + e1;
#pragma unroll
    for (int off = 32; off >= 1; off >>= 1) s += __shfl_xor(s, off);
    const float inv = 1.f / s;
    if (r0 < 32) {
      const float w = e0 * inv;
      wts[r0] = w; sidx[r0] = i0;
      outW[gq * 32 + r0] = w;
      outI[gq * 32 + r0] = (float)i0;
    }
    if (r1 < 32) {
      const float w = e1 * inv;
      wts[r1] = w; sidx[r1] = i1;
      outW[gq * 32 + r1] = w;
      outI[gq * 32 + r1] = (float)i1;
    }
  }
  __syncthreads();
  const int d = tid;
  float m = 0.f;
#pragma unroll 8
  for (int k = 0; k < 32; ++k) {
    const int si = sidx[k] & 8191;  // clamp: any logic error -> absmax, not fault
    m = fmaf(wts[k], macro[((size_t)bl * 8192 + si) * 256 + d], m);
  }
  mbar[d] = m;
  __syncthreads();
  float c = 0.f;
#pragma unroll 8
  for (int j = 0; j < 256; ++j) c = fmaf(mbar[j], wv[j * 256 + d], c);
  ctx[d] = c;
  __syncthreads();
  float y = outX[gq * 256 + d] + opb[d];  // xm stored in outX by kernel A
#pragma unroll 8
  for (int j = 0; j < 256; ++j) y = fmaf(ctx[j], opw[j * 256 + d], y);
  outX[gq * 256 + d] = y;
}

extern "C" void kernel_launch(void* const* d_in, const int* in_sizes, int n_in,
                              void* d_out, int out_size, void* d_ws, size_t ws_size,
                              hipStream_t stream) {
  const float* micro = (const float*)d_in[0];
  const float* macro = (const float*)d_in[1];
  const float* mpw   = (const float*)d_in[2];
  const float* mpb   = (const float*)d_in[3];
  const float* wq    = (const float*)d_in[4];
  const float* wk    = (const float*)d_in[5];
  // d_in[6] = wv, d_in[7] = op_w, d_in[8] = op_b
  const float* wv    = (const float*)d_in[6];
  const float* opw   = (const float*)d_in[7];
  const float* opb   = (const float*)d_in[8];

  float* outX = (float*)d_out;          // [4,2048,256]
  float* outW = outX + 2097152;         // [4,2048,32]
  float* outI = outX + 2359296;         // [4,2048,32] idx as float

  // Workspace tiers (ws_size constant across calls -> same launches every call).
  // Per batch: Q 2 MiB + K 8 MiB + topk candidates.
  int nb, lgS;
  if (ws_size >= (size_t)46 * 1024 * 1024)      { nb = 4; lgS = 1; }  // 44 MiB
  else if (ws_size >= (size_t)23 * 1024 * 1024) { nb = 2; lgS = 1; }  // 22 MiB
  else                                          { nb = 1; lgS = 2; }  // 12 MiB
  const int ncand = 32 << lgS;

  float* wsf = (float*)d_ws;
  float* Qb  = wsf;
  float* Kb  = Qb + (size_t)nb * 524288;
  float* tkv = Kb + (size_t)nb * 2097152;
  int*   tki = (int*)(tkv + (size_t)nb * 2048 * ncand);

  // x_micro for all batches -> outX region (updated in place by k_finalize)
  k_micro_mlp<<<1024, 256, 0, stream>>>(micro, mpw, mpb, outX);

  for (int b0 = 0; b0 < 4; b0 += nb) {
    k_gemm256<<<nb * 128, 256, 0, stream>>>(outX + (size_t)b0 * 524288, wq, Qb, 4);
    k_gemm256<<<nb * 512, 256, 0, stream>>>(macro + (size_t)b0 * 2097152, wk, Kb, 4);
    k_scores_topk<<<nb * 64 * (1 << lgS), 256, 0, stream>>>(Qb, Kb, tkv, tki, lgS);
    k_finalize<<<nb * 2048, 256, 0, stream>>>(macro + (size_t)b0 * 2097152, wv,
                                              tkv, tki, opw, opb, outX, outW, outI, b0, lgS);
  }
}

// Round 6
// 1419.577 us; speedup vs baseline: 1.4876x; 1.4876x over previous
//
#include <hip/hip_runtime.h>
#include <cfloat>
#include <climits>

// B=4, N_DAY=2048, N_CELLS=8192, D_MICRO=11, D=256, TOPK=32
static constexpr float SCALE = 0.0625f;  // 256^-0.5

// ---------------- kernel A: x_micro = micro @ mp_w + mp_b  → outX region ----
// (byte-identical math to the round-3 passing version)
__global__ __launch_bounds__(256) void k_micro_mlp(
    const float* __restrict__ micro, const float* __restrict__ mpw,
    const float* __restrict__ mpb, float* __restrict__ xm) {
  const int r0 = blockIdx.x * 8;
  const int tid = threadIdx.x;
  __shared__ float ml[8][12];
  if (tid < 88) ml[tid / 11][tid % 11] = micro[(size_t)(r0 + tid / 11) * 11 + tid % 11];
  __syncthreads();
  const int d = tid;
  const float bias = mpb[d];
  float acc[8];
#pragma unroll
  for (int r = 0; r < 8; ++r) acc[r] = bias;
#pragma unroll
  for (int i = 0; i < 11; ++i) {
    const float w = mpw[i * 256 + d];
#pragma unroll
    for (int r = 0; r < 8; ++r) acc[r] = fmaf(ml[r][i], w, acc[r]);
  }
#pragma unroll
  for (int r = 0; r < 8; ++r) xm[(size_t)(r0 + r) * 256 + d] = acc[r];
}

// ---------------- kernel B: C[M x 256] = A[M x 256] @ W[256 x 256] ----------
// (round-3 math, fixed ldc=256; K now gets its own buffer)
__global__ __launch_bounds__(256) void k_gemm256(
    const float* __restrict__ A, const float* __restrict__ W,
    float* __restrict__ C, int ntn) {
  const int bx = blockIdx.x;
  const int m0 = (bx / ntn) * 64, n0 = (bx % ntn) * 64;
  const int tid = threadIdx.x;
  __shared__ __align__(16) float Al[16][72];  // k-major [k][m]
  __shared__ __align__(16) float Wl[16][72];  // k-major [k][n]
  float acc[4][4] = {};
  const int mg = tid >> 4, ng = tid & 15;
  for (int k0 = 0; k0 < 256; k0 += 16) {
    __syncthreads();
    {
      const int m = tid >> 2, ko = (tid & 3) << 2;
      const float4 a = *(const float4*)&A[(size_t)(m0 + m) * 256 + k0 + ko];
      Al[ko + 0][m] = a.x; Al[ko + 1][m] = a.y; Al[ko + 2][m] = a.z; Al[ko + 3][m] = a.w;
      const int kr = tid >> 4, no = (tid & 15) << 2;
      *(float4*)&Wl[kr][no] = *(const float4*)&W[(size_t)(k0 + kr) * 256 + n0 + no];
    }
    __syncthreads();
#pragma unroll
    for (int kk = 0; kk < 16; ++kk) {
      const float4 av = *(const float4*)&Al[kk][mg << 2];
      const float4 wv = *(const float4*)&Wl[kk][ng << 2];
      const float a_[4] = {av.x, av.y, av.z, av.w};
      const float w_[4] = {wv.x, wv.y, wv.z, wv.w};
#pragma unroll
      for (int i = 0; i < 4; ++i)
#pragma unroll
        for (int j = 0; j < 4; ++j) acc[i][j] = fmaf(a_[i], w_[j], acc[i][j]);
    }
  }
#pragma unroll
  for (int i = 0; i < 4; ++i) {
    float4 o = {acc[i][0], acc[i][1], acc[i][2], acc[i][3]};
    *(float4*)&C[(size_t)(m0 + (mg << 2) + i) * 256 + n0 + (ng << 2)] = o;
  }
}

// ---------------- kernel C: fp32 scores (round-3 bit-identical) + top-32 ----
// BIT-IDENTITY CONSTRAINT: each score = single fp32 fmaf chain, k ascending
// 0..255, then *SCALE — exactly round 3's arithmetic, which passed. Do NOT
// reorder (MFMA / split-bf16 reorderings flipped near-tie ranks: r4, r5).
// Changes vs r3 are non-numeric: 4-way cell split (grid 1024 → 4 blocks/CU)
// and a cheaper sorted-lane-list selection.
__global__ __launch_bounds__(256) void k_scores_topk(
    const float* __restrict__ Q, const float* __restrict__ K,
    float* __restrict__ tkv, int* __restrict__ tki, int lgS) {
  const int wg = blockIdx.x;
  const int S = 1 << lgS;
  const int part = wg & (S - 1);
  const int qb = (wg >> lgS) & 63;
  const int bl = wg >> (lgS + 6);
  const int qloc = bl * 2048 + qb * 32;
  const float* Qb = Q + (size_t)qloc * 256;
  const float* Kb = K + (size_t)bl * 8192 * 256;
  const int cells = 8192 >> lgS;
  const int ntiles = cells >> 7;
  const int ncand = 32 << lgS;

  __shared__ __align__(16) float Qs[32][36];   // k-major [k][q]
  __shared__ __align__(16) float Kl[32][132];  // k-major [k][c]
  __shared__ __align__(16) float Sl[32][132];  // [q][c]

  const int tid = threadIdx.x;
  const int lane = tid & 63;
  const int qg = tid >> 5, cg = tid & 31;
  const int wq8 = (tid >> 6) * 8;

  // sorted top-32 in lanes 0..31 (value desc, index asc); cm = slot-31 value
  float lv[8], cm[8];
  int li[8];
#pragma unroll
  for (int qq = 0; qq < 8; ++qq) { lv[qq] = -FLT_MAX; li[qq] = 0x7fffffff; cm[qq] = -FLT_MAX; }

  for (int ct = 0; ct < ntiles; ++ct) {
    const int c0 = part * cells + ct * 128;
    float acc[4][4] = {};
    for (int kc = 0; kc < 8; ++kc) {
      const int k0 = kc * 32;
      __syncthreads();
      {
        const int q = tid >> 3, k4 = (tid & 7) << 2;
        const float4 qv = *(const float4*)&Qb[(size_t)q * 256 + k0 + k4];
        Qs[k4 + 0][q] = qv.x; Qs[k4 + 1][q] = qv.y; Qs[k4 + 2][q] = qv.z; Qs[k4 + 3][q] = qv.w;
#pragma unroll
        for (int j = 0; j < 4; ++j) {
          const int f = tid + 256 * j;
          const int c = f >> 3, kk4 = (f & 7) << 2;
          const float4 kv4 = *(const float4*)&Kb[(size_t)(c0 + c) * 256 + k0 + kk4];
          Kl[kk4 + 0][c] = kv4.x; Kl[kk4 + 1][c] = kv4.y; Kl[kk4 + 2][c] = kv4.z; Kl[kk4 + 3][c] = kv4.w;
        }
      }
      __syncthreads();
#pragma unroll 8
      for (int kk = 0; kk < 32; ++kk) {
        const float4 av = *(const float4*)&Qs[kk][qg << 2];
        const float4 bv = *(const float4*)&Kl[kk][cg << 2];
        const float a_[4] = {av.x, av.y, av.z, av.w};
        const float b_[4] = {bv.x, bv.y, bv.z, bv.w};
#pragma unroll
        for (int i = 0; i < 4; ++i)
#pragma unroll
          for (int j = 0; j < 4; ++j) acc[i][j] = fmaf(a_[i], b_[j], acc[i][j]);
      }
    }
#pragma unroll
    for (int i = 0; i < 4; ++i) {
      float4 o = {acc[i][0] * SCALE, acc[i][1] * SCALE, acc[i][2] * SCALE, acc[i][3] * SCALE};
      *(float4*)&Sl[(qg << 2) + i][cg << 2] = o;
    }
    __syncthreads();
    // ---- selection: wave owns queries wq8..wq8+7; candidates ascend in idx,
    // so every list index < cidx → tie (==) always ranks the incumbent first,
    // matching jax.lax.top_k (value desc, index asc). Accept only v > cm.
#pragma unroll
    for (int qq = 0; qq < 8; ++qq) {
      const int q = wq8 + qq;
      float cmq = cm[qq];
#pragma unroll
      for (int pass = 0; pass < 2; ++pass) {
        const float v = Sl[q][pass * 64 + lane];
        const int ci = c0 + pass * 64 + lane;
        unsigned long long mask = __ballot(v > cmq);
        while (mask) {
          const int src = __ffsll(mask) - 1;
          mask &= mask - 1;
          const float cv = __shfl(v, src);
          const int cidx = __shfl(ci, src);
          if (cv > cmq) {  // wave-uniform (cv, cmq uniform)
            const bool above = (lane < 32) &&
                (lv[qq] > cv || (lv[qq] == cv && li[qq] < cidx));
            const int p = __popcll(__ballot(above));  // insert position (prefix)
            const int pl = (lane == 0) ? 0 : lane - 1;
            const float pv = __shfl(lv[qq], pl);
            const int pi = __shfl(li[qq], pl);
            if (lane == p) { lv[qq] = cv; li[qq] = cidx; }
            else if (lane > p && lane < 32) { lv[qq] = pv; li[qq] = pi; }
            cmq = __shfl(lv[qq], 31);
          }
        }
      }
      cm[qq] = cmq;
    }
  }
#pragma unroll
  for (int qq = 0; qq < 8; ++qq) {
    if (lane < 32) {
      const size_t q = (size_t)(qloc + wq8 + qq);
      tkv[q * ncand + part * 32 + lane] = lv[qq];
      tki[q * ncand + part * 32 + lane] = li[qq];
    }
  }
}

// ---------------- kernel D: merge parts, softmax, context, output proj ------
// context = (sum_k w_k * macro[i_k]) @ wv  (V never materialized; proven r4/r5)
__global__ __launch_bounds__(256) void k_finalize(
    const float* __restrict__ macro, const float* __restrict__ wv,
    const float* __restrict__ tkv, const int* __restrict__ tki,
    const float* __restrict__ opw, const float* __restrict__ opb,
    float* __restrict__ outX, float* __restrict__ outW, float* __restrict__ outI,
    int b0, int ncand) {
  const int ql = blockIdx.x;
  const int bl = ql >> 11;
  const size_t gq = (size_t)b0 * 2048 + ql;
  const int tid = threadIdx.x;
  __shared__ float wts[32];
  __shared__ int sidx[32];
  __shared__ float mbar[256];
  __shared__ float ctx[256];
  if (tid < 32) { wts[tid] = 0.f; sidx[tid] = 0; }  // defensive
  __syncthreads();
  if (tid < 64) {
    const int lane = tid;
    float v0 = tkv[(size_t)ql * ncand + lane];
    int   i0 = tki[(size_t)ql * ncand + lane];
    float v1 = -FLT_MAX;
    int   i1 = 0x7ffe0000 + lane;  // sentinel, never rank<32
    if (ncand == 128) {
      v1 = tkv[(size_t)ql * 128 + 64 + lane];
      i1 = tki[(size_t)ql * 128 + 64 + lane];
    }
    int r0 = 0, r1 = 0;
#pragma unroll
    for (int j = 0; j < 64; ++j) {
      const float a0 = __shfl(v0, j); const int c0 = __shfl(i0, j);
      const float a1 = __shfl(v1, j); const int c1 = __shfl(i1, j);
      r0 += (a0 > v0 || (a0 == v0 && c0 < i0)) ? 1 : 0;
      r0 += (a1 > v0 || (a1 == v0 && c1 < i0)) ? 1 : 0;
      r1 += (a0 > v1 || (a0 == v1 && c0 < i1)) ? 1 : 0;
      r1 += (a1 > v1 || (a1 == v1 && c1 < i1)) ? 1 : 0;
    }
    float mv = fmaxf(v0, v1);
#pragma unroll
    for (int off = 32; off >= 1; off >>= 1) mv = fmaxf(mv, __shfl_xor(mv, off));
    const float e0 = (r0 < 32) ? expf(v0 - mv) : 0.f;
    const float e1 = (r1 < 32) ? expf(v1 - mv) : 0.f;
    float s = e0 + e1;
#pragma unroll
    for (int off = 32; off >= 1; off >>= 1) s += __shfl_xor(s, off);
    const float inv = 1.f / s;
    if (r0 < 32) {
      const float w_ = e0 * inv;
      wts[r0] = w_; sidx[r0] = i0;
      outW[gq * 32 + r0] = w_;
      outI[gq * 32 + r0] = (float)i0;
    }
    if (r1 < 32) {
      const float w_ = e1 * inv;
      wts[r1] = w_; sidx[r1] = i1;
      outW[gq * 32 + r1] = w_;
      outI[gq * 32 + r1] = (float)i1;
    }
  }
  __syncthreads();
  const int d = tid;
  float m = 0.f;
#pragma unroll 8
  for (int k = 0; k < 32; ++k) {
    const int si = sidx[k] & 8191;  // clamp: logic error → absmax, not fault
    m = fmaf(wts[k], macro[((size_t)bl * 8192 + si) * 256 + d], m);
  }
  mbar[d] = m;
  __syncthreads();
  float c = 0.f;
#pragma unroll 8
  for (int j = 0; j < 256; ++j) c = fmaf(mbar[j], wv[j * 256 + d], c);
  ctx[d] = c;
  __syncthreads();
  float y = outX[gq * 256 + d] + opb[d];  // xm stored in outX by kernel A
#pragma unroll 8
  for (int j = 0; j < 256; ++j) y = fmaf(ctx[j], opw[j * 256 + d], y);
  outX[gq * 256 + d] = y;
}

extern "C" void kernel_launch(void* const* d_in, const int* in_sizes, int n_in,
                              void* d_out, int out_size, void* d_ws, size_t ws_size,
                              hipStream_t stream) {
  const float* micro = (const float*)d_in[0];
  const float* macro = (const float*)d_in[1];
  const float* mpw   = (const float*)d_in[2];
  const float* mpb   = (const float*)d_in[3];
  const float* wq    = (const float*)d_in[4];
  const float* wk    = (const float*)d_in[5];
  const float* wv    = (const float*)d_in[6];
  const float* opw   = (const float*)d_in[7];
  const float* opb   = (const float*)d_in[8];

  float* outX = (float*)d_out;          // [4,2048,256]
  float* outW = outX + 2097152;         // [4,2048,32]
  float* outI = outX + 2359296;         // [4,2048,32] idx as float

  // Tiers (round-3 counters prove ws >= 46 MiB: its nb=4 tier ran).
  // nb=4,lgS=2: Q 8 + K 32 + cand 8 MiB = 48.4 MiB.
  int nb, lgS;
  const size_t MB = 1024 * 1024;
  if (ws_size >= 50 * MB)      { nb = 4; lgS = 2; }  // 48.4 MiB, grid 1024
  else if (ws_size >= 26 * MB) { nb = 2; lgS = 2; }  // 24.2 MiB, grid 512 x2
  else                         { nb = 1; lgS = 2; }  // 12.1 MiB, grid 256 x4
  const int ncand = 32 << lgS;  // 128

  float* Qb  = (float*)d_ws;
  float* Kb  = Qb + (size_t)nb * 524288;
  float* tkv = Kb + (size_t)nb * 2097152;
  int*   tki = (int*)(tkv + (size_t)nb * 2048 * ncand);

  // x_micro for all batches → outX region (updated in place by k_finalize)
  k_micro_mlp<<<1024, 256, 0, stream>>>(micro, mpw, mpb, outX);

  for (int b0 = 0; b0 < 4; b0 += nb) {
    k_gemm256<<<nb * 128, 256, 0, stream>>>(outX + (size_t)b0 * 524288, wq, Qb, 4);
    k_gemm256<<<nb * 512, 256, 0, stream>>>(macro + (size_t)b0 * 2097152, wk, Kb, 4);
    k_scores_topk<<<nb * 64 * (1 << lgS), 256, 0, stream>>>(Qb, Kb, tkv, tki, lgS);
    k_finalize<<<nb * 2048, 256, 0, stream>>>(macro + (size_t)b0 * 2097152, wv,
                                              tkv, tki, opw, opb, outX, outW, outI, b0, ncand);
  }
}